// Round 6
// baseline (1258.756 us; speedup 1.0000x reference)
//
#include <hip/hip_runtime.h>
#include <math.h>

#define BB 256
#define NN 1023
#define FF 8
#define HH 256
#define DEPTH 9

enum { EPI_NONE = 0, EPI_SIGMUL = 1, EPI_RELU = 2, EPI_COMBINE = 3 };

typedef __bf16 bf16x8_t __attribute__((ext_vector_type(8)));
typedef float f32x4_t __attribute__((ext_vector_type(4)));

__device__ __forceinline__ void stage16(const void* g, void* l) {
    __builtin_amdgcn_global_load_lds(
        (const __attribute__((address_space(1))) void*)g,
        (__attribute__((address_space(3))) void*)l,
        16, 0, 0);
}

// ======== 256x256 tile, BK=64, 8 waves, 8-phase counted-vmcnt schedule ======
// Per K-tile: 4 phases of {ds_read frags || one 2-load stage unit -> barrier
// -> lgkmcnt(0) -> setprio+16 MFMA -> counted vmcnt -> barrier}.
// Stage units (deadline-ordered, staged during tile t for tile t+1):
//   ph1: A-qlo   (rows 0-63 & 128-191   — acc[0-3] rows; needed t+1 ph1)
//   ph2: B-lo    (rows 0-127            — needed t+1 ph1)
//   ph3: B-hi    (rows 128-255          — needed t+1 ph1)
//   ph4: A-qhi   (rows 64-127 & 192-255 — acc[4-7] rows; needed t+1 ph3)
// Waits: vmcnt(4) end-ph2 (A-qhi(t) landed), vmcnt(2) end-ph4 (A-qlo/B(t+1)
// landed, A-qhi(t+1) still in flight). Never vmcnt(0) mid-loop.
template <int EPI>
__global__ __launch_bounds__(512, 1) void gemm256p(
    const __bf16* __restrict__ A, int lda,
    const __bf16* __restrict__ W,       // Nc x K row-major
    const float* __restrict__ bias,
    const __bf16* __restrict__ aux, int ldaux,
    void* __restrict__ Cout, int ldc,
    int K)
{
    __shared__ __bf16 lds[2][2][256 * 64];  // [buf][A=0/B=1], 128 KiB
    const int tid = threadIdx.x;
    const int lane = tid & 63;
    const int w = tid >> 6;            // 0..7
    const int wr = w >> 2, wc = w & 3; // per-wave C = 128x64

    // bijective XCD swizzle (m204)
    const int nwg = gridDim.x * gridDim.y;
    const int hw = blockIdx.y * gridDim.x + blockIdx.x;
    const int xcd = hw & 7, k0 = hw >> 3;
    const int qq = nwg >> 3, rr = nwg & 7;
    const int wg = (xcd < rr ? xcd * (qq + 1) : rr * (qq + 1) + (xcd - rr) * qq) + k0;
    const int bm0 = (wg / gridDim.x) * 256;
    const int bn0 = (wg % gridDim.x) * 256;

    const int srow = tid >> 3;                              // 0..63
    const int scolz = ((tid & 7) ^ (srow & 7)) * 8;         // inv-swizzled col

    f32x4_t acc[8][4];
#pragma unroll
    for (int i = 0; i < 8; ++i)
#pragma unroll
        for (int j = 0; j < 4; ++j) acc[i][j] = (f32x4_t){0.f, 0.f, 0.f, 0.f};

    const int rA = lane & 15;
    const int klane = (lane >> 4) * 8;
    const int rxor = (lane & 7) * 8;
    const int NT = K >> 6;

#define STAGE_A_Q(t, buf, q)                                                   \
    do {                                                                       \
        const int kk_ = (t) << 6;                                              \
        stage16(A + (size_t)(bm0 + (q) * 64 + srow) * lda + kk_ + scolz,       \
                &lds[buf][0][((q) * 64) * 64 + w * 512]);                      \
        stage16(A + (size_t)(bm0 + 128 + (q) * 64 + srow) * lda + kk_ + scolz, \
                &lds[buf][0][((128 + (q) * 64)) * 64 + w * 512]);              \
    } while (0)
#define STAGE_B_H(t, buf, hf)                                                  \
    do {                                                                       \
        const int kk_ = (t) << 6;                                              \
        stage16(W + (size_t)(bn0 + (hf) * 128 + srow) * K + kk_ + scolz,       \
                &lds[buf][1][((hf) * 128) * 64 + w * 512]);                    \
        stage16(W + (size_t)(bn0 + (hf) * 128 + 64 + srow) * K + kk_ + scolz,  \
                &lds[buf][1][((hf) * 128 + 64) * 64 + w * 512]);               \
    } while (0)

#define LDA_F(As_, i, ks) \
    (*(const bf16x8_t*)&(As_)[(wr * 128 + (i) * 16 + rA) * 64 + (((ks) * 32 + klane) ^ rxor)])
#define LDB_F(Bs_, j, ks) \
    (*(const bf16x8_t*)&(Bs_)[(wc * 64 + (j) * 16 + rA) * 64 + (((ks) * 32 + klane) ^ rxor)])

#define PHASE_OPEN()                         \
    __builtin_amdgcn_sched_barrier(0);       \
    __builtin_amdgcn_s_barrier();            \
    asm volatile("s_waitcnt lgkmcnt(0)" ::: "memory"); \
    __builtin_amdgcn_sched_barrier(0);       \
    __builtin_amdgcn_s_setprio(1)
#define PHASE_CLOSE()                        \
    __builtin_amdgcn_s_setprio(0);           \
    __builtin_amdgcn_sched_barrier(0);       \
    __builtin_amdgcn_s_barrier();            \
    __builtin_amdgcn_sched_barrier(0)

    // prologue: stage all of tile 0, drain, barrier.
    STAGE_A_Q(0, 0, 0);
    STAGE_A_Q(0, 0, 1);
    STAGE_B_H(0, 0, 0);
    STAGE_B_H(0, 0, 1);
    asm volatile("s_waitcnt vmcnt(0)" ::: "memory");
    __builtin_amdgcn_sched_barrier(0);
    __builtin_amdgcn_s_barrier();
    __builtin_amdgcn_sched_barrier(0);

    for (int t = 0; t < NT; ++t) {
        const int c = t & 1, n = c ^ 1;
        const __bf16* As = lds[c][0];
        const __bf16* Bs = lds[c][1];
        const bool more = (t + 1 < NT);
        bf16x8_t a0[4], a1[4], b0[4], b1[4];

        // ---- phase 1: acc[0-3] x ks0 ----
#pragma unroll
        for (int j = 0; j < 4; ++j) b0[j] = LDB_F(Bs, j, 0);
#pragma unroll
        for (int i = 0; i < 4; ++i) a0[i] = LDA_F(As, i, 0);
        if (more) STAGE_A_Q(t + 1, n, 0);
        PHASE_OPEN();
#pragma unroll
        for (int i = 0; i < 4; ++i)
#pragma unroll
            for (int j = 0; j < 4; ++j)
                acc[i][j] = __builtin_amdgcn_mfma_f32_16x16x32_bf16(
                    a0[i], b0[j], acc[i][j], 0, 0, 0);
        PHASE_CLOSE();

        // ---- phase 2: acc[0-3] x ks1 ----
#pragma unroll
        for (int j = 0; j < 4; ++j) b1[j] = LDB_F(Bs, j, 1);
#pragma unroll
        for (int i = 0; i < 4; ++i) a1[i] = LDA_F(As, i, 1);
        if (more) STAGE_B_H(t + 1, n, 0);
        PHASE_OPEN();
#pragma unroll
        for (int i = 0; i < 4; ++i)
#pragma unroll
            for (int j = 0; j < 4; ++j)
                acc[i][j] = __builtin_amdgcn_mfma_f32_16x16x32_bf16(
                    a1[i], b1[j], acc[i][j], 0, 0, 0);
        __builtin_amdgcn_s_setprio(0);
        if (more) {
            asm volatile("s_waitcnt vmcnt(4)" ::: "memory");  // A-qhi(t) landed
        } else {
            asm volatile("s_waitcnt vmcnt(0)" ::: "memory");
        }
        __builtin_amdgcn_sched_barrier(0);
        __builtin_amdgcn_s_barrier();
        __builtin_amdgcn_sched_barrier(0);

        // ---- phase 3: acc[4-7] x ks0 ----
#pragma unroll
        for (int i = 0; i < 4; ++i) a0[i] = LDA_F(As, 4 + i, 0);
        if (more) STAGE_B_H(t + 1, n, 1);
        PHASE_OPEN();
#pragma unroll
        for (int i = 0; i < 4; ++i)
#pragma unroll
            for (int j = 0; j < 4; ++j)
                acc[4 + i][j] = __builtin_amdgcn_mfma_f32_16x16x32_bf16(
                    a0[i], b0[j], acc[4 + i][j], 0, 0, 0);
        PHASE_CLOSE();

        // ---- phase 4: acc[4-7] x ks1 ----
#pragma unroll
        for (int i = 0; i < 4; ++i) a1[i] = LDA_F(As, 4 + i, 1);
        if (more) STAGE_A_Q(t + 1, n, 1);
        PHASE_OPEN();
#pragma unroll
        for (int i = 0; i < 4; ++i)
#pragma unroll
            for (int j = 0; j < 4; ++j)
                acc[4 + i][j] = __builtin_amdgcn_mfma_f32_16x16x32_bf16(
                    a1[i], b1[j], acc[4 + i][j], 0, 0, 0);
        __builtin_amdgcn_s_setprio(0);
        if (more) {
            // A-qlo/B-lo/B-hi(t+1) landed; A-qhi(t+1) stays in flight.
            asm volatile("s_waitcnt vmcnt(2)" ::: "memory");
        }
        __builtin_amdgcn_sched_barrier(0);
        __builtin_amdgcn_s_barrier();
        __builtin_amdgcn_sched_barrier(0);
    }
#undef STAGE_A_Q
#undef STAGE_B_H
#undef LDA_F
#undef LDB_F
#undef PHASE_OPEN
#undef PHASE_CLOSE

    if (EPI == EPI_COMBINE) {
        const int r = lane & 15;
        const int G = ((bn0 + wc * 64) >> 2) + r;
        float bz4[4];
#pragma unroll
        for (int g = 0; g < 4; ++g) bz4[g] = bias[bn0 + wc * 64 + g * 16 + r];
#pragma unroll
        for (int i = 0; i < 8; ++i) {
#pragma unroll
            for (int reg = 0; reg < 4; ++reg) {
                const int gr = bm0 + wr * 128 + i * 16 + (lane >> 4) * 4 + reg;
                float z0 = acc[i][0][reg] + bz4[0];
                float z1 = acc[i][1][reg] + bz4[1];
                float z2 = acc[i][2][reg] + bz4[2];
                float z3 = acc[i][3][reg] + bz4[3];
                float mx = fmaxf(fmaxf(z0, z1), fmaxf(z2, z3));
                float e0 = __expf(z0 - mx), e1 = __expf(z1 - mx);
                float e2 = __expf(z2 - mx), e3 = __expf(z3 - mx);
                const __bf16* hrow = aux + (size_t)gr * ldaux + G;
                float hv = (e0 * (float)hrow[0] + e1 * (float)hrow[256] +
                            e2 * (float)hrow[512] + e3 * (float)hrow[768]) /
                           (e0 + e1 + e2 + e3);
                ((__bf16*)Cout)[(size_t)gr * ldc + G] = (__bf16)hv;
            }
        }
    } else {
#pragma unroll
        for (int j = 0; j < 4; ++j) {
            const int gc = bn0 + wc * 64 + j * 16 + (lane & 15);
            const float bv = bias[gc];
#pragma unroll
            for (int i = 0; i < 8; ++i) {
#pragma unroll
                for (int reg = 0; reg < 4; ++reg) {
                    const int gr = bm0 + wr * 128 + i * 16 + (lane >> 4) * 4 + reg;
                    float v = acc[i][j][reg] + bv;
                    if (EPI == EPI_SIGMUL) {
                        float s = 1.0f / (1.0f + __expf(-v));
                        v = s * (float)aux[(size_t)gr * ldaux + gc];
                        ((__bf16*)Cout)[(size_t)gr * ldc + gc] = (__bf16)v;
                    } else if (EPI == EPI_RELU) {
                        v = fmaxf(v, 0.0f);
                        ((__bf16*)Cout)[(size_t)gr * ldc + gc] = (__bf16)v;
                    } else {
                        ((float*)Cout)[(size_t)gr * ldc + gc] = v;
                    }
                }
            }
        }
    }
}

// ---------------- 128x128-tile kernel (proven; Wh + small levels) -----------
template <int EPI>
__global__ __launch_bounds__(256) void gemm_mfma(
    const __bf16* __restrict__ A, int lda,
    const __bf16* __restrict__ W,
    const float* __restrict__ bias,
    const __bf16* __restrict__ aux, int ldaux,
    void* __restrict__ Cout, int ldc,
    int K)
{
    __shared__ __bf16 As[128 * 32];
    __shared__ __bf16 Bs[128 * 32];
    const int tid = threadIdx.x;
    const int lane = tid & 63;
    const int w = tid >> 6;
    const int wr = w >> 1, wc = w & 1;

    const int nwg = gridDim.x * gridDim.y;
    const int hw = blockIdx.y * gridDim.x + blockIdx.x;
    const int xcd = hw & 7, k0 = hw >> 3;
    const int qq = nwg >> 3, rr = nwg & 7;
    const int wg = (xcd < rr ? xcd * (qq + 1) : rr * (qq + 1) + (xcd - rr) * qq) + k0;
    const int bm0 = (wg / gridDim.x) * 128;
    const int bn0 = (wg % gridDim.x) * 128;

    const int srow = lane >> 2;
    const int scol = (lane & 3) * 8;

    f32x4_t acc[4][4];
#pragma unroll
    for (int i = 0; i < 4; ++i)
#pragma unroll
        for (int j = 0; j < 4; ++j) acc[i][j] = (f32x4_t){0.f, 0.f, 0.f, 0.f};

    const int rA = lane & 15;
    const int kslot = (lane >> 4) * 8;

    for (int kk = 0; kk < K; kk += 32) {
        stage16(A + (size_t)(bm0 + w * 16 + srow) * lda + kk + scol,
                &As[(w * 16) * 32]);
        stage16(A + (size_t)(bm0 + 64 + w * 16 + srow) * lda + kk + scol,
                &As[(64 + w * 16) * 32]);
        stage16(W + (size_t)(bn0 + w * 16 + srow) * K + kk + scol,
                &Bs[(w * 16) * 32]);
        stage16(W + (size_t)(bn0 + 64 + w * 16 + srow) * K + kk + scol,
                &Bs[(64 + w * 16) * 32]);
        __syncthreads();

        bf16x8_t af[4], bfr[4];
#pragma unroll
        for (int i = 0; i < 4; ++i)
            af[i] = *(const bf16x8_t*)&As[(wr * 64 + i * 16 + rA) * 32 + kslot];
#pragma unroll
        for (int j = 0; j < 4; ++j)
            bfr[j] = *(const bf16x8_t*)&Bs[(wc * 64 + j * 16 + rA) * 32 + kslot];
#pragma unroll
        for (int i = 0; i < 4; ++i)
#pragma unroll
            for (int j = 0; j < 4; ++j)
                acc[i][j] = __builtin_amdgcn_mfma_f32_16x16x32_bf16(
                    af[i], bfr[j], acc[i][j], 0, 0, 0);
        __syncthreads();
    }

    if (EPI == EPI_COMBINE) {
        const int r = lane & 15;
        const int G = ((bn0 + wc * 64) >> 2) + r;
        float bz4[4];
#pragma unroll
        for (int g = 0; g < 4; ++g) bz4[g] = bias[bn0 + wc * 64 + g * 16 + r];
#pragma unroll
        for (int i = 0; i < 4; ++i) {
#pragma unroll
            for (int reg = 0; reg < 4; ++reg) {
                const int gr = bm0 + wr * 64 + i * 16 + (lane >> 4) * 4 + reg;
                float z0 = acc[i][0][reg] + bz4[0];
                float z1 = acc[i][1][reg] + bz4[1];
                float z2 = acc[i][2][reg] + bz4[2];
                float z3 = acc[i][3][reg] + bz4[3];
                float mx = fmaxf(fmaxf(z0, z1), fmaxf(z2, z3));
                float e0 = __expf(z0 - mx), e1 = __expf(z1 - mx);
                float e2 = __expf(z2 - mx), e3 = __expf(z3 - mx);
                const __bf16* hrow = aux + (size_t)gr * ldaux + G;
                float hv = (e0 * (float)hrow[0] + e1 * (float)hrow[256] +
                            e2 * (float)hrow[512] + e3 * (float)hrow[768]) /
                           (e0 + e1 + e2 + e3);
                ((__bf16*)Cout)[(size_t)gr * ldc + G] = (__bf16)hv;
            }
        }
    } else {
#pragma unroll
        for (int j = 0; j < 4; ++j) {
            const int gc = bn0 + wc * 64 + j * 16 + (lane & 15);
            const float bv = bias[gc];
#pragma unroll
            for (int i = 0; i < 4; ++i) {
#pragma unroll
                for (int reg = 0; reg < 4; ++reg) {
                    const int gr = bm0 + wr * 64 + i * 16 + (lane >> 4) * 4 + reg;
                    float v = acc[i][j][reg] + bv;
                    if (EPI == EPI_SIGMUL) {
                        float s = 1.0f / (1.0f + __expf(-v));
                        v = s * (float)aux[(size_t)gr * ldaux + gc];
                        ((__bf16*)Cout)[(size_t)gr * ldc + gc] = (__bf16)v;
                    } else if (EPI == EPI_RELU) {
                        v = fmaxf(v, 0.0f);
                        ((__bf16*)Cout)[(size_t)gr * ldc + gc] = (__bf16)v;
                    } else {
                        ((float*)Cout)[(size_t)gr * ldc + gc] = v;
                    }
                }
            }
        }
    }
}

// Wr/Wh -> bf16; Wz -> bf16 with softmax-group row permutation.
__global__ __launch_bounds__(256) void convert_weights(
    const float* __restrict__ Wr, const float* __restrict__ Wh,
    const float* __restrict__ Wz, const float* __restrict__ bz,
    __bf16* __restrict__ Wrb, __bf16* __restrict__ Whb,
    __bf16* __restrict__ Wzb, float* __restrict__ bzp)
{
    const int NR = 768 * 768, NH2 = 256 * 768, NZ = 1024 * 1024;
    const int idx0 = blockIdx.x * 256 + threadIdx.x;
    for (int i = idx0; i < NR + NH2 + NZ; i += gridDim.x * 256) {
        if (i < NR) Wrb[i] = (__bf16)Wr[i];
        else if (i < NR + NH2) Whb[i - NR] = (__bf16)Wh[i - NR];
        else {
            const int z = i - NR - NH2;
            const int p = z >> 10, k = z & 1023;
            const int o = ((p >> 4) & 3) * 256 + (p >> 6) * 16 + (p & 15);
            Wzb[z] = (__bf16)Wz[(size_t)o * 1024 + k];
        }
    }
    if (idx0 < 1024) {
        const int p = idx0;
        const int o = ((p >> 4) & 3) * 256 + (p >> 6) * 16 + (p & 15);
        bzp[p] = bz[o];
    }
}

// hhhu cols 256..1024 = [parent_u, h_l, h_r]; 8 rows/block, 8 cols/thread.
__global__ __launch_bounds__(256) void build_hhu(
    const float* __restrict__ data, const float* __restrict__ Wu,
    const float* __restrict__ bu, const __bf16* __restrict__ hprev,
    __bf16* __restrict__ hhhu, int l, int r0)
{
    const int n = 1 << l;
    const int row = blockIdx.x * 8 + (threadIdx.x >> 5);
    const int c0 = (threadIdx.x & 31) * 8;
    const int i = r0 + row;
    const int b = i >> l;
    const int m = i & (n - 1);

    float wv[8][8];
#pragma unroll
    for (int cc = 0; cc < 8; ++cc) {
        float4 w0 = *(const float4*)&Wu[(c0 + cc) * 8];
        float4 w1 = *(const float4*)&Wu[(c0 + cc) * 8 + 4];
        wv[cc][0] = w0.x; wv[cc][1] = w0.y; wv[cc][2] = w0.z; wv[cc][3] = w0.w;
        wv[cc][4] = w1.x; wv[cc][5] = w1.y; wv[cc][6] = w1.z; wv[cc][7] = w1.w;
    }
    float buv[8];
#pragma unroll
    for (int cc = 0; cc < 8; ++cc) buv[cc] = bu[c0 + cc];

    __bf16* rowp = hhhu + (size_t)row * 1024;

    {
        const float* dp = data + ((size_t)b * NN + (n - 1) + m) * FF;
        float4 d0 = *(const float4*)dp, d1 = *(const float4*)(dp + 4);
        float dv[8] = {d0.x, d0.y, d0.z, d0.w, d1.x, d1.y, d1.z, d1.w};
        bf16x8_t o;
#pragma unroll
        for (int cc = 0; cc < 8; ++cc) {
            float acc = buv[cc];
#pragma unroll
            for (int f = 0; f < 8; ++f) acc += dv[f] * wv[cc][f];
            o[cc] = (__bf16)acc;
        }
        *(bf16x8_t*)&rowp[256 + c0] = o;
    }

    if (l == 8) {
        const float* dl = data + ((size_t)b * NN + 511 + 2 * m) * FF;
#pragma unroll
        for (int side = 0; side < 2; ++side) {
            const float* dp = dl + side * FF;
            float4 d0 = *(const float4*)dp, d1 = *(const float4*)(dp + 4);
            float dv[8] = {d0.x, d0.y, d0.z, d0.w, d1.x, d1.y, d1.z, d1.w};
            bf16x8_t o;
#pragma unroll
            for (int cc = 0; cc < 8; ++cc) {
                float acc = buv[cc];
#pragma unroll
                for (int f = 0; f < 8; ++f) acc += dv[f] * wv[cc][f];
                o[cc] = (__bf16)acc;
            }
            *(bf16x8_t*)&rowp[512 + side * 256 + c0] = o;
        }
    } else {
        *(bf16x8_t*)&rowp[512 + c0] =
            *(const bf16x8_t*)&hprev[((size_t)b * (2 * n) + 2 * m) * HH + c0];
        *(bf16x8_t*)&rowp[768 + c0] =
            *(const bf16x8_t*)&hprev[((size_t)b * (2 * n) + 2 * m + 1) * HH + c0];
    }
}

__global__ __launch_bounds__(256) void final_kernel(
    const __bf16* __restrict__ hfin, const float* __restrict__ Wp,
    const float* __restrict__ bp, float* __restrict__ out)
{
    const int b = blockIdx.x;
    const int t = threadIdx.x;
    __shared__ float red[256];
    red[t] = (float)hfin[(size_t)b * HH + t] * Wp[t];
    __syncthreads();
    for (int s = 128; s > 0; s >>= 1) {
        if (t < s) red[t] += red[t + s];
        __syncthreads();
    }
    if (t == 0) out[b] = red[0] + bp[0];
}

extern "C" void kernel_launch(void* const* d_in, const int* in_sizes, int n_in,
                              void* d_out, int out_size, void* d_ws, size_t ws_size,
                              hipStream_t stream)
{
    const float* data = (const float*)d_in[0];
    const float* Wu = (const float*)d_in[1];
    const float* bu = (const float*)d_in[2];
    const float* Wr = (const float*)d_in[3];
    const float* br = (const float*)d_in[4];
    const float* Wh = (const float*)d_in[5];
    const float* bh = (const float*)d_in[6];
    const float* Wz = (const float*)d_in[7];
    const float* bz = (const float*)d_in[8];
    const float* Wp = (const float*)d_in[9];
    const float* bp = (const float*)d_in[10];
    float* out = (float*)d_out;

    const size_t CAP = 32768;
    char* w = (char*)d_ws;
    __bf16* hA = (__bf16*)w;   w += (size_t)65536 * HH * 2;
    __bf16* hB = (__bf16*)w;   w += (size_t)32768 * HH * 2;
    __bf16* hhhu = (__bf16*)w; w += CAP * 1024 * 2;
    __bf16* rh = (__bf16*)w;   w += CAP * 768 * 2;
    __bf16* Wrb = (__bf16*)w;  w += (size_t)768 * 768 * 2;
    __bf16* Whb = (__bf16*)w;  w += (size_t)256 * 768 * 2;
    __bf16* Wzb = (__bf16*)w;  w += (size_t)1024 * 1024 * 2;
    float* bzp = (float*)w;    w += 1024 * 4;

    convert_weights<<<2048, 256, 0, stream>>>(Wr, Wh, Wz, bz, Wrb, Whb, Wzb, bzp);

    for (int l = DEPTH - 1; l >= 0; --l) {
        const size_t M = (size_t)BB << l;
        __bf16* dst = ((DEPTH - 1 - l) & 1) ? hB : hA;
        const __bf16* src = ((DEPTH - 1 - l) & 1) ? hA : hB;  // unused at l=8
        for (size_t r0 = 0; r0 < M; r0 += CAP) {
            const int R = (int)((M - r0 < CAP) ? (M - r0) : CAP);
            build_hhu<<<R / 8, 256, 0, stream>>>(data, Wu, bu, src, hhhu, l, (int)r0);
            if (R >= 2048) {
                gemm256p<EPI_SIGMUL><<<dim3(3, R / 256), 512, 0, stream>>>(
                    hhhu + 256, 1024, Wrb, br, hhhu + 256, 1024, rh, 768, 768);
            } else {
                gemm_mfma<EPI_SIGMUL><<<dim3(6, R / 128), 256, 0, stream>>>(
                    hhhu + 256, 1024, Wrb, br, hhhu + 256, 1024, rh, 768, 768);
            }
            gemm_mfma<EPI_RELU><<<dim3(2, R / 128), 256, 0, stream>>>(
                rh, 768, Whb, bh, nullptr, 0, hhhu, 1024, 768);
            if (R >= 2048) {
                gemm256p<EPI_COMBINE><<<dim3(4, R / 256), 512, 0, stream>>>(
                    hhhu, 1024, Wzb, bzp, hhhu, 1024,
                    dst + (size_t)r0 * HH, HH, 1024);
            } else {
                gemm_mfma<EPI_COMBINE><<<dim3(8, R / 128), 256, 0, stream>>>(
                    hhhu, 1024, Wzb, bzp, hhhu, 1024,
                    dst + (size_t)r0 * HH, HH, 1024);
            }
        }
    }
    final_kernel<<<BB, 256, 0, stream>>>(hA, Wp, bp, out);
}

// Round 7
// 1250.348 us; speedup vs baseline: 1.0067x; 1.0067x over previous
//
#include <hip/hip_runtime.h>
#include <math.h>

#define BB 256
#define NN 1023
#define FF 8
#define HH 256
#define DEPTH 9

enum { EPI_NONE = 0, EPI_SIGMUL = 1, EPI_RELU = 2, EPI_COMBINE = 3 };

typedef __bf16 bf16x8_t __attribute__((ext_vector_type(8)));
typedef float f32x4_t __attribute__((ext_vector_type(4)));

__device__ __forceinline__ void stage16(const void* g, void* l) {
    __builtin_amdgcn_global_load_lds(
        (const __attribute__((address_space(1))) void*)g,
        (__attribute__((address_space(3))) void*)l,
        16, 0, 0);
}

__device__ __forceinline__ int xcd_remap(int hw, int nwg) {
    const int xcd = hw & 7, k0 = hw >> 3;
    const int qq = nwg >> 3, rr = nwg & 7;
    return (xcd < rr ? xcd * (qq + 1) : rr * (qq + 1) + (xcd - rr) * qq) + k0;
}

// ======== 256x256 tile, BK=64, 8 waves, 4-phase counted-vmcnt schedule ======
// m201 phase skeleton WITHOUT sched_barrier pinning (m141: pinning = -42%).
// Phase = {ds_read frags ; one 2-load stage unit ; s_barrier ; lgkmcnt(0) ;
// setprio(1) ; 16 MFMA ; setprio(0) ; [counted vmcnt] ; s_barrier}.
// Stage units during tile t for t+1 (deadline order): ph1 A-qlo, ph2 B-lo,
// ph3 B-hi, ph4 A-qhi. Waits: vmcnt(4) end-ph2 (A-qhi(t) landed before ph3
// reads), vmcnt(2) end-ph4 (A-qlo/B(t+1) landed, A-qhi(t+1) in flight).
// Per-wave vmcnt before the block-wide barrier => collective guarantee.
template <int EPI>
__global__ __launch_bounds__(512, 1) void gemm256p(
    const __bf16* __restrict__ A, int lda,
    const __bf16* __restrict__ W,       // Nc x K row-major
    const float* __restrict__ bias,
    const __bf16* __restrict__ aux, int ldaux,
    void* __restrict__ Cout, int ldc,
    int K)
{
    __shared__ __bf16 lds[2][2][256 * 64];  // [buf][A=0/B=1], 128 KiB
    const int tid = threadIdx.x;
    const int lane = tid & 63;
    const int w = tid >> 6;            // 0..7
    const int wr = w >> 2, wc = w & 3; // per-wave C = 128x64

    const int nwg = gridDim.x * gridDim.y;
    const int hw = blockIdx.y * gridDim.x + blockIdx.x;
    const int wg = xcd_remap(hw, nwg);
    const int bm0 = (wg / gridDim.x) * 256;
    const int bn0 = (wg % gridDim.x) * 256;

    const int srow = tid >> 3;                              // 0..63
    const int scolz = ((tid & 7) ^ (srow & 7)) * 8;         // inv-swizzled col

    f32x4_t acc[8][4];
#pragma unroll
    for (int i = 0; i < 8; ++i)
#pragma unroll
        for (int j = 0; j < 4; ++j) acc[i][j] = (f32x4_t){0.f, 0.f, 0.f, 0.f};

    const int rA = lane & 15;
    const int klane = (lane >> 4) * 8;
    const int rxor = (lane & 7) * 8;
    const int NT = K >> 6;

#define STAGE_A_Q(t, buf, q)                                                   \
    do {                                                                       \
        const int kk_ = (t) << 6;                                              \
        stage16(A + (size_t)(bm0 + (q) * 64 + srow) * lda + kk_ + scolz,       \
                &lds[buf][0][((q) * 64) * 64 + w * 512]);                      \
        stage16(A + (size_t)(bm0 + 128 + (q) * 64 + srow) * lda + kk_ + scolz, \
                &lds[buf][0][((128 + (q) * 64)) * 64 + w * 512]);              \
    } while (0)
#define STAGE_B_H(t, buf, hf)                                                  \
    do {                                                                       \
        const int kk_ = (t) << 6;                                              \
        stage16(W + (size_t)(bn0 + (hf) * 128 + srow) * K + kk_ + scolz,       \
                &lds[buf][1][((hf) * 128) * 64 + w * 512]);                    \
        stage16(W + (size_t)(bn0 + (hf) * 128 + 64 + srow) * K + kk_ + scolz,  \
                &lds[buf][1][((hf) * 128 + 64) * 64 + w * 512]);               \
    } while (0)

#define LDA_F(As_, i, ks) \
    (*(const bf16x8_t*)&(As_)[(wr * 128 + (i) * 16 + rA) * 64 + (((ks) * 32 + klane) ^ rxor)])
#define LDB_F(Bs_, j, ks) \
    (*(const bf16x8_t*)&(Bs_)[(wc * 64 + (j) * 16 + rA) * 64 + (((ks) * 32 + klane) ^ rxor)])

    // prologue: stage tile 0 in deadline order; keep A-qhi(0) in flight.
    STAGE_A_Q(0, 0, 0);
    STAGE_B_H(0, 0, 0);
    STAGE_B_H(0, 0, 1);
    STAGE_A_Q(0, 0, 1);
    asm volatile("s_waitcnt vmcnt(2)" ::: "memory");
    __builtin_amdgcn_s_barrier();

    for (int t = 0; t < NT; ++t) {
        const int c = t & 1, n = c ^ 1;
        const __bf16* As = lds[c][0];
        const __bf16* Bs = lds[c][1];
        const bool more = (t + 1 < NT);
        bf16x8_t a0[4], a1[4], b0[4], b1[4];

        // ---- phase 1: acc[0-3] x ks0 ----
#pragma unroll
        for (int j = 0; j < 4; ++j) b0[j] = LDB_F(Bs, j, 0);
#pragma unroll
        for (int i = 0; i < 4; ++i) a0[i] = LDA_F(As, i, 0);
        if (more) STAGE_A_Q(t + 1, n, 0);
        __builtin_amdgcn_s_barrier();
        asm volatile("s_waitcnt lgkmcnt(0)" ::: "memory");
        __builtin_amdgcn_s_setprio(1);
#pragma unroll
        for (int i = 0; i < 4; ++i)
#pragma unroll
            for (int j = 0; j < 4; ++j)
                acc[i][j] = __builtin_amdgcn_mfma_f32_16x16x32_bf16(
                    a0[i], b0[j], acc[i][j], 0, 0, 0);
        __builtin_amdgcn_s_setprio(0);
        __builtin_amdgcn_s_barrier();

        // ---- phase 2: acc[0-3] x ks1 ----
#pragma unroll
        for (int j = 0; j < 4; ++j) b1[j] = LDB_F(Bs, j, 1);
#pragma unroll
        for (int i = 0; i < 4; ++i) a1[i] = LDA_F(As, i, 1);
        if (more) STAGE_B_H(t + 1, n, 0);
        __builtin_amdgcn_s_barrier();
        asm volatile("s_waitcnt lgkmcnt(0)" ::: "memory");
        __builtin_amdgcn_s_setprio(1);
#pragma unroll
        for (int i = 0; i < 4; ++i)
#pragma unroll
            for (int j = 0; j < 4; ++j)
                acc[i][j] = __builtin_amdgcn_mfma_f32_16x16x32_bf16(
                    a1[i], b1[j], acc[i][j], 0, 0, 0);
        __builtin_amdgcn_s_setprio(0);
        if (more) {
            asm volatile("s_waitcnt vmcnt(4)" ::: "memory");  // A-qhi(t) landed
        } else {
            asm volatile("s_waitcnt vmcnt(0)" ::: "memory");
        }
        __builtin_amdgcn_s_barrier();

        // ---- phase 3: acc[4-7] x ks0 ----
#pragma unroll
        for (int i = 0; i < 4; ++i) a0[i] = LDA_F(As, 4 + i, 0);
        if (more) STAGE_B_H(t + 1, n, 1);
        __builtin_amdgcn_s_barrier();
        asm volatile("s_waitcnt lgkmcnt(0)" ::: "memory");
        __builtin_amdgcn_s_setprio(1);
#pragma unroll
        for (int i = 0; i < 4; ++i)
#pragma unroll
            for (int j = 0; j < 4; ++j)
                acc[4 + i][j] = __builtin_amdgcn_mfma_f32_16x16x32_bf16(
                    a0[i], b0[j], acc[4 + i][j], 0, 0, 0);
        __builtin_amdgcn_s_setprio(0);
        __builtin_amdgcn_s_barrier();

        // ---- phase 4: acc[4-7] x ks1 ----
#pragma unroll
        for (int i = 0; i < 4; ++i) a1[i] = LDA_F(As, 4 + i, 1);
        if (more) STAGE_A_Q(t + 1, n, 1);
        __builtin_amdgcn_s_barrier();
        asm volatile("s_waitcnt lgkmcnt(0)" ::: "memory");
        __builtin_amdgcn_s_setprio(1);
#pragma unroll
        for (int i = 0; i < 4; ++i)
#pragma unroll
            for (int j = 0; j < 4; ++j)
                acc[4 + i][j] = __builtin_amdgcn_mfma_f32_16x16x32_bf16(
                    a1[i], b1[j], acc[4 + i][j], 0, 0, 0);
        __builtin_amdgcn_s_setprio(0);
        if (more) {
            // A-qlo/B-lo/B-hi(t+1) landed; A-qhi(t+1) stays in flight.
            asm volatile("s_waitcnt vmcnt(2)" ::: "memory");
            __builtin_amdgcn_s_barrier();
        }
    }
#undef STAGE_A_Q
#undef STAGE_B_H
#undef LDA_F
#undef LDB_F

    if (EPI == EPI_COMBINE) {
        const int r = lane & 15;
        const int G = ((bn0 + wc * 64) >> 2) + r;
        float bz4[4];
#pragma unroll
        for (int g = 0; g < 4; ++g) bz4[g] = bias[bn0 + wc * 64 + g * 16 + r];
#pragma unroll
        for (int i = 0; i < 8; ++i) {
#pragma unroll
            for (int reg = 0; reg < 4; ++reg) {
                const int gr = bm0 + wr * 128 + i * 16 + (lane >> 4) * 4 + reg;
                float z0 = acc[i][0][reg] + bz4[0];
                float z1 = acc[i][1][reg] + bz4[1];
                float z2 = acc[i][2][reg] + bz4[2];
                float z3 = acc[i][3][reg] + bz4[3];
                float mx = fmaxf(fmaxf(z0, z1), fmaxf(z2, z3));
                float e0 = __expf(z0 - mx), e1 = __expf(z1 - mx);
                float e2 = __expf(z2 - mx), e3 = __expf(z3 - mx);
                const __bf16* hrow = aux + (size_t)gr * ldaux + G;
                float hv = (e0 * (float)hrow[0] + e1 * (float)hrow[256] +
                            e2 * (float)hrow[512] + e3 * (float)hrow[768]) /
                           (e0 + e1 + e2 + e3);
                ((__bf16*)Cout)[(size_t)gr * ldc + G] = (__bf16)hv;
            }
        }
    } else {
#pragma unroll
        for (int j = 0; j < 4; ++j) {
            const int gc = bn0 + wc * 64 + j * 16 + (lane & 15);
            const float bv = bias[gc];
#pragma unroll
            for (int i = 0; i < 8; ++i) {
#pragma unroll
                for (int reg = 0; reg < 4; ++reg) {
                    const int gr = bm0 + wr * 128 + i * 16 + (lane >> 4) * 4 + reg;
                    float v = acc[i][j][reg] + bv;
                    if (EPI == EPI_SIGMUL) {
                        float s = 1.0f / (1.0f + __expf(-v));
                        v = s * (float)aux[(size_t)gr * ldaux + gc];
                        ((__bf16*)Cout)[(size_t)gr * ldc + gc] = (__bf16)v;
                    } else if (EPI == EPI_RELU) {
                        v = fmaxf(v, 0.0f);
                        ((__bf16*)Cout)[(size_t)gr * ldc + gc] = (__bf16)v;
                    } else {
                        ((float*)Cout)[(size_t)gr * ldc + gc] = v;
                    }
                }
            }
        }
    }
}

// ---------------- 128x128-tile kernel (proven; Wh + small levels) -----------
template <int EPI>
__global__ __launch_bounds__(256) void gemm_mfma(
    const __bf16* __restrict__ A, int lda,
    const __bf16* __restrict__ W,
    const float* __restrict__ bias,
    const __bf16* __restrict__ aux, int ldaux,
    void* __restrict__ Cout, int ldc,
    int K)
{
    __shared__ __bf16 As[128 * 32];
    __shared__ __bf16 Bs[128 * 32];
    const int tid = threadIdx.x;
    const int lane = tid & 63;
    const int w = tid >> 6;
    const int wr = w >> 1, wc = w & 1;

    const int nwg = gridDim.x * gridDim.y;
    const int hw = blockIdx.y * gridDim.x + blockIdx.x;
    const int wg = xcd_remap(hw, nwg);
    const int bm0 = (wg / gridDim.x) * 128;
    const int bn0 = (wg % gridDim.x) * 128;

    const int srow = lane >> 2;
    const int scol = (lane & 3) * 8;

    f32x4_t acc[4][4];
#pragma unroll
    for (int i = 0; i < 4; ++i)
#pragma unroll
        for (int j = 0; j < 4; ++j) acc[i][j] = (f32x4_t){0.f, 0.f, 0.f, 0.f};

    const int rA = lane & 15;
    const int kslot = (lane >> 4) * 8;

    for (int kk = 0; kk < K; kk += 32) {
        stage16(A + (size_t)(bm0 + w * 16 + srow) * lda + kk + scol,
                &As[(w * 16) * 32]);
        stage16(A + (size_t)(bm0 + 64 + w * 16 + srow) * lda + kk + scol,
                &As[(64 + w * 16) * 32]);
        stage16(W + (size_t)(bn0 + w * 16 + srow) * K + kk + scol,
                &Bs[(w * 16) * 32]);
        stage16(W + (size_t)(bn0 + 64 + w * 16 + srow) * K + kk + scol,
                &Bs[(64 + w * 16) * 32]);
        __syncthreads();

        bf16x8_t af[4], bfr[4];
#pragma unroll
        for (int i = 0; i < 4; ++i)
            af[i] = *(const bf16x8_t*)&As[(wr * 64 + i * 16 + rA) * 32 + kslot];
#pragma unroll
        for (int j = 0; j < 4; ++j)
            bfr[j] = *(const bf16x8_t*)&Bs[(wc * 64 + j * 16 + rA) * 32 + kslot];
#pragma unroll
        for (int i = 0; i < 4; ++i)
#pragma unroll
            for (int j = 0; j < 4; ++j)
                acc[i][j] = __builtin_amdgcn_mfma_f32_16x16x32_bf16(
                    af[i], bfr[j], acc[i][j], 0, 0, 0);
        __syncthreads();
    }

    if (EPI == EPI_COMBINE) {
        const int r = lane & 15;
        const int G = ((bn0 + wc * 64) >> 2) + r;
        float bz4[4];
#pragma unroll
        for (int g = 0; g < 4; ++g) bz4[g] = bias[bn0 + wc * 64 + g * 16 + r];
#pragma unroll
        for (int i = 0; i < 4; ++i) {
#pragma unroll
            for (int reg = 0; reg < 4; ++reg) {
                const int gr = bm0 + wr * 64 + i * 16 + (lane >> 4) * 4 + reg;
                float z0 = acc[i][0][reg] + bz4[0];
                float z1 = acc[i][1][reg] + bz4[1];
                float z2 = acc[i][2][reg] + bz4[2];
                float z3 = acc[i][3][reg] + bz4[3];
                float mx = fmaxf(fmaxf(z0, z1), fmaxf(z2, z3));
                float e0 = __expf(z0 - mx), e1 = __expf(z1 - mx);
                float e2 = __expf(z2 - mx), e3 = __expf(z3 - mx);
                const __bf16* hrow = aux + (size_t)gr * ldaux + G;
                float hv = (e0 * (float)hrow[0] + e1 * (float)hrow[256] +
                            e2 * (float)hrow[512] + e3 * (float)hrow[768]) /
                           (e0 + e1 + e2 + e3);
                ((__bf16*)Cout)[(size_t)gr * ldc + G] = (__bf16)hv;
            }
        }
    } else {
#pragma unroll
        for (int j = 0; j < 4; ++j) {
            const int gc = bn0 + wc * 64 + j * 16 + (lane & 15);
            const float bv = bias[gc];
#pragma unroll
            for (int i = 0; i < 4; ++i) {
#pragma unroll
                for (int reg = 0; reg < 4; ++reg) {
                    const int gr = bm0 + wr * 64 + i * 16 + (lane >> 4) * 4 + reg;
                    float v = acc[i][j][reg] + bv;
                    if (EPI == EPI_SIGMUL) {
                        float s = 1.0f / (1.0f + __expf(-v));
                        v = s * (float)aux[(size_t)gr * ldaux + gc];
                        ((__bf16*)Cout)[(size_t)gr * ldc + gc] = (__bf16)v;
                    } else if (EPI == EPI_RELU) {
                        v = fmaxf(v, 0.0f);
                        ((__bf16*)Cout)[(size_t)gr * ldc + gc] = (__bf16)v;
                    } else {
                        ((float*)Cout)[(size_t)gr * ldc + gc] = v;
                    }
                }
            }
        }
    }
}

// Wr/Wh -> bf16; Wz -> bf16 with softmax-group row permutation.
__global__ __launch_bounds__(256) void convert_weights(
    const float* __restrict__ Wr, const float* __restrict__ Wh,
    const float* __restrict__ Wz, const float* __restrict__ bz,
    __bf16* __restrict__ Wrb, __bf16* __restrict__ Whb,
    __bf16* __restrict__ Wzb, float* __restrict__ bzp)
{
    const int NR = 768 * 768, NH2 = 256 * 768, NZ = 1024 * 1024;
    const int idx0 = blockIdx.x * 256 + threadIdx.x;
    for (int i = idx0; i < NR + NH2 + NZ; i += gridDim.x * 256) {
        if (i < NR) Wrb[i] = (__bf16)Wr[i];
        else if (i < NR + NH2) Whb[i - NR] = (__bf16)Wh[i - NR];
        else {
            const int z = i - NR - NH2;
            const int p = z >> 10, k = z & 1023;
            const int o = ((p >> 4) & 3) * 256 + (p >> 6) * 16 + (p & 15);
            Wzb[z] = (__bf16)Wz[(size_t)o * 1024 + k];
        }
    }
    if (idx0 < 1024) {
        const int p = idx0;
        const int o = ((p >> 4) & 3) * 256 + (p >> 6) * 16 + (p & 15);
        bzp[p] = bz[o];
    }
}

// hhhu cols 256..1024 = [parent_u, h_l, h_r]; 8 rows/block, 8 cols/thread.
// Block index XCD-remapped so producer rows land on the same XCD L2 as the
// consumer GEMM's A-panels.
__global__ __launch_bounds__(256) void build_hhu(
    const float* __restrict__ data, const float* __restrict__ Wu,
    const float* __restrict__ bu, const __bf16* __restrict__ hprev,
    __bf16* __restrict__ hhhu, int l, int r0)
{
    const int n = 1 << l;
    const int blk = xcd_remap(blockIdx.x, gridDim.x);
    const int row = blk * 8 + (threadIdx.x >> 5);
    const int c0 = (threadIdx.x & 31) * 8;
    const int i = r0 + row;
    const int b = i >> l;
    const int m = i & (n - 1);

    float wv[8][8];
#pragma unroll
    for (int cc = 0; cc < 8; ++cc) {
        float4 w0 = *(const float4*)&Wu[(c0 + cc) * 8];
        float4 w1 = *(const float4*)&Wu[(c0 + cc) * 8 + 4];
        wv[cc][0] = w0.x; wv[cc][1] = w0.y; wv[cc][2] = w0.z; wv[cc][3] = w0.w;
        wv[cc][4] = w1.x; wv[cc][5] = w1.y; wv[cc][6] = w1.z; wv[cc][7] = w1.w;
    }
    float buv[8];
#pragma unroll
    for (int cc = 0; cc < 8; ++cc) buv[cc] = bu[c0 + cc];

    __bf16* rowp = hhhu + (size_t)row * 1024;

    {
        const float* dp = data + ((size_t)b * NN + (n - 1) + m) * FF;
        float4 d0 = *(const float4*)dp, d1 = *(const float4*)(dp + 4);
        float dv[8] = {d0.x, d0.y, d0.z, d0.w, d1.x, d1.y, d1.z, d1.w};
        bf16x8_t o;
#pragma unroll
        for (int cc = 0; cc < 8; ++cc) {
            float acc = buv[cc];
#pragma unroll
            for (int f = 0; f < 8; ++f) acc += dv[f] * wv[cc][f];
            o[cc] = (__bf16)acc;
        }
        *(bf16x8_t*)&rowp[256 + c0] = o;
    }

    if (l == 8) {
        const float* dl = data + ((size_t)b * NN + 511 + 2 * m) * FF;
#pragma unroll
        for (int side = 0; side < 2; ++side) {
            const float* dp = dl + side * FF;
            float4 d0 = *(const float4*)dp, d1 = *(const float4*)(dp + 4);
            float dv[8] = {d0.x, d0.y, d0.z, d0.w, d1.x, d1.y, d1.z, d1.w};
            bf16x8_t o;
#pragma unroll
            for (int cc = 0; cc < 8; ++cc) {
                float acc = buv[cc];
#pragma unroll
                for (int f = 0; f < 8; ++f) acc += dv[f] * wv[cc][f];
                o[cc] = (__bf16)acc;
            }
            *(bf16x8_t*)&rowp[512 + side * 256 + c0] = o;
        }
    } else {
        *(bf16x8_t*)&rowp[512 + c0] =
            *(const bf16x8_t*)&hprev[((size_t)b * (2 * n) + 2 * m) * HH + c0];
        *(bf16x8_t*)&rowp[768 + c0] =
            *(const bf16x8_t*)&hprev[((size_t)b * (2 * n) + 2 * m + 1) * HH + c0];
    }
}

__global__ __launch_bounds__(256) void final_kernel(
    const __bf16* __restrict__ hfin, const float* __restrict__ Wp,
    const float* __restrict__ bp, float* __restrict__ out)
{
    const int b = blockIdx.x;
    const int t = threadIdx.x;
    __shared__ float red[256];
    red[t] = (float)hfin[(size_t)b * HH + t] * Wp[t];
    __syncthreads();
    for (int s = 128; s > 0; s >>= 1) {
        if (t < s) red[t] += red[t + s];
        __syncthreads();
    }
    if (t == 0) out[b] = red[0] + bp[0];
}

extern "C" void kernel_launch(void* const* d_in, const int* in_sizes, int n_in,
                              void* d_out, int out_size, void* d_ws, size_t ws_size,
                              hipStream_t stream)
{
    const float* data = (const float*)d_in[0];
    const float* Wu = (const float*)d_in[1];
    const float* bu = (const float*)d_in[2];
    const float* Wr = (const float*)d_in[3];
    const float* br = (const float*)d_in[4];
    const float* Wh = (const float*)d_in[5];
    const float* bh = (const float*)d_in[6];
    const float* Wz = (const float*)d_in[7];
    const float* bz = (const float*)d_in[8];
    const float* Wp = (const float*)d_in[9];
    const float* bp = (const float*)d_in[10];
    float* out = (float*)d_out;

    const size_t CAP = 32768;
    char* w = (char*)d_ws;
    __bf16* hA = (__bf16*)w;   w += (size_t)65536 * HH * 2;
    __bf16* hB = (__bf16*)w;   w += (size_t)32768 * HH * 2;
    __bf16* hhhu = (__bf16*)w; w += CAP * 1024 * 2;
    __bf16* rh = (__bf16*)w;   w += CAP * 768 * 2;
    __bf16* Wrb = (__bf16*)w;  w += (size_t)768 * 768 * 2;
    __bf16* Whb = (__bf16*)w;  w += (size_t)256 * 768 * 2;
    __bf16* Wzb = (__bf16*)w;  w += (size_t)1024 * 1024 * 2;
    float* bzp = (float*)w;    w += 1024 * 4;

    convert_weights<<<2048, 256, 0, stream>>>(Wr, Wh, Wz, bz, Wrb, Whb, Wzb, bzp);

    for (int l = DEPTH - 1; l >= 0; --l) {
        const size_t M = (size_t)BB << l;
        __bf16* dst = ((DEPTH - 1 - l) & 1) ? hB : hA;
        const __bf16* src = ((DEPTH - 1 - l) & 1) ? hA : hB;  // unused at l=8
        for (size_t r0 = 0; r0 < M; r0 += CAP) {
            const int R = (int)((M - r0 < CAP) ? (M - r0) : CAP);
            build_hhu<<<R / 8, 256, 0, stream>>>(data, Wu, bu, src, hhhu, l, (int)r0);
            if (R >= 2048) {
                gemm256p<EPI_SIGMUL><<<dim3(3, R / 256), 512, 0, stream>>>(
                    hhhu + 256, 1024, Wrb, br, hhhu + 256, 1024, rh, 768, 768);
            } else {
                gemm_mfma<EPI_SIGMUL><<<dim3(6, R / 128), 256, 0, stream>>>(
                    hhhu + 256, 1024, Wrb, br, hhhu + 256, 1024, rh, 768, 768);
            }
            gemm_mfma<EPI_RELU><<<dim3(2, R / 128), 256, 0, stream>>>(
                rh, 768, Whb, bh, nullptr, 0, hhhu, 1024, 768);
            if (R >= 2048) {
                gemm256p<EPI_COMBINE><<<dim3(4, R / 256), 512, 0, stream>>>(
                    hhhu, 1024, Wzb, bzp, hhhu, 1024,
                    dst + (size_t)r0 * HH, HH, 1024);
            } else {
                gemm_mfma<EPI_COMBINE><<<dim3(8, R / 128), 256, 0, stream>>>(
                    hhhu, 1024, Wzb, bzp, hhhu, 1024,
                    dst + (size_t)r0 * HH, HH, 1024);
            }
        }
    }
    final_kernel<<<BB, 256, 0, stream>>>(hA, Wp, bp, out);
}